// Round 7
// baseline (334.310 us; speedup 1.0000x reference)
//
#include <hip/hip_runtime.h>

#define EPS 1e-5f
#define BATCH 524288
#define BLK 256
#define RBLK 1024            // k_reduce_x blocks
#define NPREP 60             // k_prep blocks (60*256 == AF_TOT)
#define NBLK2 4096           // k_lstm blocks (128 batch each)
#define NBLKO 2048           // k_out blocks

typedef float f32x4 __attribute__((ext_vector_type(4)));
typedef __bf16 bf16x8 __attribute__((ext_vector_type(8)));

// ---- ws layout: ushort A-frag tables occupy float [0, 7680) ----
#define AF_A0    0           // 10 frags x 512 ushort (layer0; k24 = bias0)
#define AF_A1K0  5120        // 10 frags x 512 (layer1 k 0..31)
#define AF_A1K1  10240       // 10 frags x 512 padded (k' 0..7 = h1 tail, k'8 = bias1)
#define AF_TOT   15360
#define OFF_ACC  7680        // floats: [0..5] sum_t, [6..11] sumsq_t, [12] S2, [13] Q2

__device__ __forceinline__ float sigm(float x) {
    return __builtin_amdgcn_rcpf(1.0f + __expf(-x));
}
__device__ __forceinline__ float tanh_f(float x) {
    return 1.0f - 2.0f * __builtin_amdgcn_rcpf(1.0f + __expf(2.0f * x));
}
__device__ __forceinline__ float wave_reduce(float v) {
    #pragma unroll
    for (int o = 32; o; o >>= 1) v += __shfl_down(v, o, 64);
    return v;
}

struct HiLo { bf16x8 hi, lo; };
__device__ __forceinline__ HiLo cvt8(f32x4 a, f32x4 b) {
    HiLo r;
    #pragma unroll
    for (int i = 0; i < 4; ++i) {
        float v = a[i];
        __bf16 h = (__bf16)v;
        r.hi[i] = h; r.lo[i] = (__bf16)(v - (float)h);
        float w = b[i];
        __bf16 h2 = (__bf16)w;
        r.hi[4 + i] = h2; r.lo[4 + i] = (__bf16)(w - (float)h2);
    }
    return r;
}
#define MFMA16(C_, A_, B_) \
    (C_) = __builtin_amdgcn_mfma_f32_16x16x32_bf16((A_), (B_), (C_), 0, 0, 0)

// ---------------- Kernel 0: build A-fragments (bias folded in) + zero accums ----
// C/D row rr = 4*q + g <-> (d = 4*tm + q, gate g); wrow = g*20 + d.
// Fragment element i of lane l: k = 4*(l>>4) + (i&3) + 16*(i>>2), m-row = l&15.
// Layer0 k-map: k<20 Whh0 | k<24 Wih0 | k==24 bias0 | else 0.
// Layer1 K0  : k<20 Wih1 | k<40... (k-20)<20 Whh1.
// Layer1 K1  : k'= 4q+(i&3)+16(i>>2); q<2,i<4 -> Whh1[.][12+4q+i]; k'==8 -> bias1; else 0.
__global__ __launch_bounds__(BLK) void k_prep(
    const float* __restrict__ Wih0, const float* __restrict__ Whh0,
    const float* __restrict__ bih0, const float* __restrict__ bhh0,
    const float* __restrict__ Wih1, const float* __restrict__ Whh1,
    const float* __restrict__ bih1, const float* __restrict__ bhh1,
    float* __restrict__ ws) {
    int gtid = blockIdx.x * BLK + threadIdx.x;
    unsigned short* af = (unsigned short*)ws;
    if (gtid < AF_TOT) {
        int idx = gtid;
        float w = 0.f; int s;
        if (idx < AF_A1K0) {                 // layer0
            int e = idx, fid = e >> 9; e &= 511;
            int l = e >> 3, i = e & 7;
            int tm = fid >> 1; s = fid & 1;
            int q = l >> 4, m = l & 15;
            int wrow = (m & 3) * 20 + 4 * tm + (m >> 2);
            int k = 4 * q + (i & 3) + 16 * (i >> 2);
            w = (k < 20) ? Whh0[wrow * 20 + k]
              : (k < 24) ? Wih0[wrow * 4 + (k - 20)]
              : (k == 24) ? (bih0[wrow] + bhh0[wrow]) : 0.f;
        } else if (idx < AF_A1K1) {          // layer1 K-tile0
            int e = idx - AF_A1K0, fid = e >> 9; e &= 511;
            int l = e >> 3, i = e & 7;
            int tm = fid >> 1; s = fid & 1;
            int q = l >> 4, m = l & 15;
            int wrow = (m & 3) * 20 + 4 * tm + (m >> 2);
            int k = 4 * q + (i & 3) + 16 * (i >> 2);
            w = (k < 20) ? Wih1[wrow * 20 + k] : Whh1[wrow * 20 + (k - 20)];
        } else {                             // layer1 K-tile1 (padded)
            int e = idx - AF_A1K1, fid = e >> 9; e &= 511;
            int l = e >> 3, i = e & 7;
            int tm = fid >> 1; s = fid & 1;
            int q = l >> 4, m = l & 15;
            int wrow = (m & 3) * 20 + 4 * tm + (m >> 2);
            w = (q < 2 && i < 4) ? Whh1[wrow * 20 + 12 + 4 * q + i]
              : (q == 2 && i == 0) ? (bih1[wrow] + bhh1[wrow]) : 0.f;
        }
        float fh = (float)(__bf16)w;
        float v = s ? (w - fh) : w;
        af[idx] = __builtin_bit_cast(unsigned short, (__bf16)v);
    }
    if (gtid < 16) ws[OFF_ACC + gtid] = 0.f;   // zero BN accumulators
}

// ---------------- Kernel 1: BN1 sums of x (grid-stride + atomics) ----------------
__global__ __launch_bounds__(BLK) void k_reduce_x(const float* __restrict__ x,
                                                  float* __restrict__ acc) {
    float s[6], q[6];
    #pragma unroll
    for (int t = 0; t < 6; ++t) { s[t] = 0.f; q[t] = 0.f; }
    for (int b = blockIdx.x * BLK + threadIdx.x; b < BATCH; b += RBLK * BLK) {
        const float4* xp = (const float4*)(x + (size_t)b * 24);
        #pragma unroll
        for (int t = 0; t < 6; ++t) {
            float4 v = xp[t];
            s[t] += (v.x + v.y) + (v.z + v.w);
            q[t] += (v.x * v.x + v.y * v.y) + (v.z * v.z + v.w * v.w);
        }
    }
    __shared__ float red[4 * 12];
    int wid = threadIdx.x >> 6, lane = threadIdx.x & 63;
    #pragma unroll
    for (int c = 0; c < 6; ++c) {
        float rs = wave_reduce(s[c]);
        float rq = wave_reduce(q[c]);
        if (lane == 0) { red[wid * 12 + c] = rs; red[wid * 12 + 6 + c] = rq; }
    }
    __syncthreads();
    if (threadIdx.x < 12) {
        float tot = red[threadIdx.x] + red[12 + threadIdx.x] +
                    red[24 + threadIdx.x] + red[36 + threadIdx.x];
        atomicAdd(&acc[threadIdx.x], tot);
    }
}

// ---------------- Kernel 2: MFMA LSTM (A-frags resident in VGPRs) ----------------
// Per wave: 32 batch (2 N-tiles). A-frag/bias tables live in registers across
// the t-loop (t-invariant). LDS = per-wave bounce buffer only (h transpose).
__global__ __launch_bounds__(BLK, 1) void k_lstm(
    const float* __restrict__ x,
    const float* __restrict__ wsT,
    const float* __restrict__ gamma, const float* __restrict__ beta,
    const float* __restrict__ Wout,
    float* __restrict__ dotout, float* __restrict__ acc2) {
    __shared__ __align__(16) float sBounce[4 * 1408];   // 22528 B

    const int tid = threadIdx.x;
    const int wid = tid >> 6, lane = tid & 63;
    const int q = lane >> 4, col = lane & 15;
    const int wb = blockIdx.x * 128 + wid * 32;
    float* buf = sBounce + wid * 1408;
    float* bc0 = buf + col * 44;          // N-tile 0 column base
    float* bc1 = bc0 + 16 * 44;           // N-tile 1

    // ---- A-fragments -> registers (once; coalesced 16B/lane global loads) ----
    const unsigned short* af = (const unsigned short*)wsT;
    bf16x8 A0h[5], A0l[5], A1h[5], A1l[5], A2h[5], A2l[5];
    #pragma unroll
    for (int tm = 0; tm < 5; ++tm) {
        A0h[tm] = *(const bf16x8*)(af + AF_A0   + (2 * tm) * 512 + lane * 8);
        A0l[tm] = *(const bf16x8*)(af + AF_A0   + (2 * tm + 1) * 512 + lane * 8);
        A1h[tm] = *(const bf16x8*)(af + AF_A1K0 + (2 * tm) * 512 + lane * 8);
        A1l[tm] = *(const bf16x8*)(af + AF_A1K0 + (2 * tm + 1) * 512 + lane * 8);
        A2h[tm] = *(const bf16x8*)(af + AF_A1K1 + (2 * tm) * 512 + lane * 8);
        A2l[tm] = *(const bf16x8*)(af + AF_A1K1 + (2 * tm + 1) * 512 + lane * 8);
    }
    const float* accp = wsT + OFF_ACC;

    for (int m = lane; m < 1408; m += 64) buf[m] = 0.f;  // per-wave: no barrier

    float c0s[5][2], c1s[5][2];
    #pragma unroll
    for (int tm = 0; tm < 5; ++tm)
        #pragma unroll
        for (int nt = 0; nt < 2; ++nt) { c0s[tm][nt] = 0.f; c1s[tm][nt] = 0.f; }

    const float* xb0 = x + (size_t)(wb + col) * 24 + q;
    const float* xb1 = x + (size_t)(wb + 16 + col) * 24 + q;
    float x0c = xb0[0], x1c = xb1[0];

    #pragma unroll 1
    for (int t = 0; t < 6; ++t) {
        // BN1 coefficients from global sums (uniform -> scalar path)
        const float invN = 1.0f / ((float)BATCH * 4.0f);
        float mean = accp[t] * invN;
        float var = accp[6 + t] * invN - mean * mean;
        float inv = rsqrtf(var + EPS);
        float at = gamma[t] * inv;
        float bt = beta[t] - mean * at;

        float x0n = 0.f, x1n = 0.f;
        if (t < 5) { x0n = xb0[(t + 1) * 4]; x1n = xb1[(t + 1) * 4]; }  // prefetch
        bc0[40 + q] = fmaf(at, x0c, bt);   // x rows 40..43
        bc1[40 + q] = fmaf(at, x1c, bt);

        // ---- layer 0 B-frags: lower k=4q (h0); upper q0->h0[16..19], q1->x, q2->bias-one
        HiLo b0[2];
        #pragma unroll
        for (int nt = 0; nt < 2; ++nt) {
            const float* bp = nt ? bc1 : bc0;
            f32x4 va = *(const f32x4*)(bp + 4 * q);
            f32x4 vb = {0.f, 0.f, 0.f, 0.f};
            if (q < 2) vb = *(const f32x4*)(bp + (q ? 40 : 16));
            else if (q == 2) vb[0] = 1.0f;            // bias column k=24
            b0[nt] = cvt8(va, vb);
        }
        #pragma unroll
        for (int tm = 0; tm < 5; ++tm) {
            #pragma unroll
            for (int nt = 0; nt < 2; ++nt) {
                f32x4 c = {0.f, 0.f, 0.f, 0.f};       // bias via MFMA
                MFMA16(c, A0h[tm], b0[nt].hi);
                MFMA16(c, A0h[tm], b0[nt].lo);
                MFMA16(c, A0l[tm], b0[nt].hi);
                float ii = sigm(c[0]), ff = sigm(c[1]);
                float gg = tanh_f(c[2]), oo = sigm(c[3]);
                float cn = fmaf(ff, c0s[tm][nt], ii * gg);
                c0s[tm][nt] = cn;
                (nt ? bc1 : bc0)[4 * tm + q] = oo * tanh_f(cn);   // h0 rows 0..19
            }
        }

        // ---- layer 1 B-frags: K0 = rows 0..31; K1 = rows 32..39 + bias-one (q==2)
        HiLo b1[2], b2[2];
        #pragma unroll
        for (int nt = 0; nt < 2; ++nt) {
            const float* bp = nt ? bc1 : bc0;
            f32x4 va = *(const f32x4*)(bp + 4 * q);
            f32x4 vb = *(const f32x4*)(bp + 16 + 4 * q);
            b1[nt] = cvt8(va, vb);
            f32x4 vc = {0.f, 0.f, 0.f, 0.f};
            if (q < 2) vc = *(const f32x4*)(bp + 32 + 4 * q);
            else if (q == 2) vc[0] = 1.0f;            // bias column k'=8
            f32x4 vz = {0.f, 0.f, 0.f, 0.f};
            b2[nt] = cvt8(vc, vz);
        }
        #pragma unroll
        for (int tm = 0; tm < 5; ++tm) {
            #pragma unroll
            for (int nt = 0; nt < 2; ++nt) {
                f32x4 c = {0.f, 0.f, 0.f, 0.f};
                MFMA16(c, A1h[tm], b1[nt].hi);
                MFMA16(c, A1h[tm], b1[nt].lo);
                MFMA16(c, A1l[tm], b1[nt].hi);
                MFMA16(c, A2h[tm], b2[nt].hi);
                MFMA16(c, A2h[tm], b2[nt].lo);
                MFMA16(c, A2l[tm], b2[nt].hi);
                float ii = sigm(c[0]), ff = sigm(c[1]);
                float gg = tanh_f(c[2]), oo = sigm(c[3]);
                float cn = fmaf(ff, c1s[tm][nt], ii * gg);
                c1s[tm][nt] = cn;
                (nt ? bc1 : bc0)[20 + 4 * tm + q] = oo * tanh_f(cn);  // h1 rows
            }
        }
        x0c = x0n; x1c = x1n;
    }

    // ---- epilogue: head dot + BN2 partials (h1 final read from bounce) ----
    float wout[5];
    #pragma unroll
    for (int tm = 0; tm < 5; ++tm) wout[tm] = Wout[4 * tm + q];
    float psum = 0.f, psq = 0.f;
    float dsum[2];
    #pragma unroll
    for (int nt = 0; nt < 2; ++nt) {
        const float* bp = nt ? bc1 : bc0;
        float d = 0.f;
        #pragma unroll
        for (int tm = 0; tm < 5; ++tm) {
            float v = bp[20 + 4 * tm + q];
            d = fmaf(v, wout[tm], d);
            psum += v; psq = fmaf(v, v, psq);
        }
        d += __shfl_xor(d, 16);
        d += __shfl_xor(d, 32);
        dsum[nt] = d;
    }
    if (q == 0) {
        dotout[wb + col] = dsum[0];
        dotout[wb + 16 + col] = dsum[1];
    }
    psum = wave_reduce(psum);
    psq = wave_reduce(psq);
    __syncthreads();
    if (lane == 0) { sBounce[wid] = psum; sBounce[4 + wid] = psq; }
    __syncthreads();
    if (tid == 0) {
        atomicAdd(&acc2[0], sBounce[0] + sBounce[1] + sBounce[2] + sBounce[3]);
        atomicAdd(&acc2[1], sBounce[4] + sBounce[5] + sBounce[6] + sBounce[7]);
    }
}

// ---------------- Kernel 3: out = s1*dot + s2 (s1,s2 derived inline) ----------------
__global__ __launch_bounds__(BLK) void k_out(float* __restrict__ out,
                                             const float* __restrict__ ws,
                                             const float* __restrict__ gamma,
                                             const float* __restrict__ beta,
                                             const float* __restrict__ Wout,
                                             const float* __restrict__ bout) {
    float S = ws[OFF_ACC + 12], Q = ws[OFF_ACC + 13];
    const float N = (float)BATCH * 20.0f;
    float m = S / N, var = Q / N - m * m;
    float s1 = gamma[5] * rsqrtf(var + EPS);
    float sw = 0.f;
    #pragma unroll
    for (int h = 0; h < 20; ++h) sw += Wout[h];
    float s2 = (beta[5] - m * s1) * sw + bout[0];
    int i = blockIdx.x * BLK + threadIdx.x;
    out[i] = s1 * out[i] + s2;
}

extern "C" void kernel_launch(void* const* d_in, const int* in_sizes, int n_in,
                              void* d_out, int out_size, void* d_ws, size_t ws_size,
                              hipStream_t stream) {
    const float* x     = (const float*)d_in[0];
    const float* gamma = (const float*)d_in[1];
    const float* beta  = (const float*)d_in[2];
    const float* Wih0  = (const float*)d_in[3];
    const float* Whh0  = (const float*)d_in[4];
    const float* bih0  = (const float*)d_in[5];
    const float* bhh0  = (const float*)d_in[6];
    const float* Wih1  = (const float*)d_in[7];
    const float* Whh1  = (const float*)d_in[8];
    const float* bih1  = (const float*)d_in[9];
    const float* bhh1  = (const float*)d_in[10];
    const float* Wout  = (const float*)d_in[11];
    const float* bout  = (const float*)d_in[12];
    float* out = (float*)d_out;
    float* ws = (float*)d_ws;

    k_prep<<<NPREP, BLK, 0, stream>>>(Wih0, Whh0, bih0, bhh0,
                                      Wih1, Whh1, bih1, bhh1, ws);
    k_reduce_x<<<RBLK, BLK, 0, stream>>>(x, ws + OFF_ACC);
    k_lstm<<<NBLK2, BLK, 0, stream>>>(x, ws, gamma, beta, Wout,
                                      out, ws + OFF_ACC + 12);
    k_out<<<NBLKO, BLK, 0, stream>>>(out, ws, gamma, beta, Wout, bout);
}